// Round 3
// baseline (106.499 us; speedup 1.0000x reference)
//
#include <hip/hip_runtime.h>
#include <math.h>

#define F 128
#define D 256
#define N_CATE 18
#define P 8

// ---------------- sort pipeline: counting sort of edges by key = d*N_CATE + c --------

__global__ void zero_kernel(int* __restrict__ p, int n) {
    int i = blockIdx.x * blockDim.x + threadIdx.x;
    if (i < n) p[i] = 0;
}

__global__ void hist_kernel(const int* __restrict__ src_idx,
                            const int* __restrict__ dst_idx,
                            const int* __restrict__ cate_id,
                            int* __restrict__ keys, int* __restrict__ cnt, int E) {
    int e = blockIdx.x * blockDim.x + threadIdx.x;
    if (e >= E) return;
    int s = src_idx[e];
    int k = dst_idx[e] * N_CATE + cate_id[s];
    keys[e] = k;
    atomicAdd(&cnt[k], 1);
}

// per-1024-chunk totals
__global__ __launch_bounds__(256) void scan_block_totals(const int* __restrict__ cnt,
                                                         int* __restrict__ blk, int nkey) {
    int b = blockIdx.x, t = threadIdx.x;
    int lane = t & 63, wid = t >> 6;
    int base = b * 1024 + t * 4;
    int s = 0;
#pragma unroll
    for (int i = 0; i < 4; ++i) { int idx = base + i; if (idx < nkey) s += cnt[idx]; }
#pragma unroll
    for (int m = 1; m < 64; m <<= 1) s += __shfl_xor(s, m, 64);
    __shared__ int lds[4];
    if (lane == 0) lds[wid] = s;
    __syncthreads();
    if (t == 0) blk[b] = lds[0] + lds[1] + lds[2] + lds[3];
}

// exclusive scan of chunk totals (nblk <= 256, single block)
__global__ __launch_bounds__(256) void scan_totals(int* __restrict__ blk, int nblk) {
    int t = threadIdx.x, lane = t & 63, wid = t >> 6;
    int v = (t < nblk) ? blk[t] : 0;
    int x = v;
#pragma unroll
    for (int m = 1; m < 64; m <<= 1) { int y = __shfl_up(x, m, 64); if (lane >= m) x += y; }
    __shared__ int lds[4];
    if (lane == 63) lds[wid] = x;
    __syncthreads();
    int off = 0;
    for (int w = 0; w < wid; ++w) off += lds[w];
    if (t < nblk) blk[t] = x - v + off;
}

// turn cnt[] into global exclusive offsets
__global__ __launch_bounds__(256) void scan_apply(int* __restrict__ cnt,
                                                  const int* __restrict__ blk, int nkey) {
    int b = blockIdx.x, t = threadIdx.x;
    int lane = t & 63, wid = t >> 6;
    int base = b * 1024 + t * 4;
    int c[4]; int ts = 0;
#pragma unroll
    for (int i = 0; i < 4; ++i) { int idx = base + i; c[i] = (idx < nkey) ? cnt[idx] : 0; ts += c[i]; }
    int x = ts;
#pragma unroll
    for (int m = 1; m < 64; m <<= 1) { int y = __shfl_up(x, m, 64); if (lane >= m) x += y; }
    __shared__ int lds[4];
    if (lane == 63) lds[wid] = x;
    __syncthreads();
    int off = blk[b];
    for (int w = 0; w < wid; ++w) off += lds[w];
    int excl = off + x - ts;
#pragma unroll
    for (int i = 0; i < 4; ++i) {
        int idx = base + i;
        if (idx < nkey) { cnt[idx] = excl; excl += c[i]; }
    }
}

__global__ void scatter_kernel(const int* __restrict__ keys, int* __restrict__ cnt,
                               int* __restrict__ order, int E) {
    int e = blockIdx.x * blockDim.x + threadIdx.x;
    if (e >= E) return;
    int pos = atomicAdd(&cnt[keys[e]], 1);
    order[pos] = e;
}

// ---------------- main kernel --------------------------------------------------------
// Lane layout: lane = 8*p + j. out = sqrt(F) * softmax-weighted mean of s_p,
// s_p = (w_p*(src.pref_p) + (1-w_p)*(src.dst)) / sqrt(F).
__global__ __launch_bounds__(256) void score_predictor_kernel(
    const float* __restrict__ gnn_emb_src,   // (N_SRC, D)
    const float* __restrict__ gnn_emb_dst,   // (N_DST, D)
    const float* __restrict__ news_pref,     // (N_DST, N_CATE, P, D)
    const float* __restrict__ last_update,   // (N_DST, N_CATE, P)
    const float* __restrict__ time_arr,      // (E,)
    const int*   __restrict__ cate_id,       // (N_SRC,)
    const int*   __restrict__ src_idx,       // (E,)
    const int*   __restrict__ dst_idx,       // (E,)
    const int*   __restrict__ order,         // (E,) sorted-edge permutation (or NULL)
    float* __restrict__ out,
    int E)
{
    // bijective chunked XCD swizzle: each XCD gets a contiguous range of sorted edges
    const int B = (int)gridDim.x;
    const int bid = (int)blockIdx.x;
    const int q = B >> 3, r = B & 7;
    const int xcd = bid & 7, pos = bid >> 3;
    const int nb = (xcd < r) ? (xcd * (q + 1)) : (r * (q + 1) + (xcd - r) * q);
    const int sb = nb + pos;

    const int w = sb * 4 + (int)(threadIdx.x >> 6);
    const int lane = (int)(threadIdx.x & 63);
    if (w >= E) return;
    const int e = order ? order[w] : w;
    const int p = lane >> 3;
    const int j = lane & 7;

    const int s = src_idx[e];
    const int d = dst_idx[e];
    const int c = cate_id[s];
    const float t0 = time_arr[0];

    const float* __restrict__ srow = gnn_emb_src + (size_t)s * D;
    const float* __restrict__ drow = gnn_emb_dst + (size_t)d * D;
    const size_t dc = (size_t)d * N_CATE + (size_t)c;
    const float* __restrict__ prow = news_pref + dc * (size_t)(P * D) + (size_t)p * D;

    const float wp = __expf(last_update[dc * P + p] - t0);
    const float omw = 1.0f - wp;

    float qp = 0.0f, tp = 0.0f;
#pragma unroll
    for (int k = 0; k < 4; ++k) {
        const int off = k * 32 + j * 4;
        const float4 sv = *(const float4*)(srow + off);
        const float4 dv = *(const float4*)(drow + off);
        const float4 pv = *(const float4*)(prow + off);
        qp += sv.x * pv.x + sv.y * pv.y + sv.z * pv.z + sv.w * pv.w;
        tp += sv.x * dv.x + sv.y * dv.y + sv.z * dv.z + sv.w * dv.w;
    }

#pragma unroll
    for (int m = 1; m <= 4; m <<= 1) {
        qp += __shfl_xor(qp, m, 64);
        tp += __shfl_xor(tp, m, 64);
    }

    const float inv_sqrtF = 0.088388347648318447f; // 1/sqrt(128)
    const float sp = (wp * qp + omw * tp) * inv_sqrtF;

    float mx = sp;
#pragma unroll
    for (int m = 8; m <= 32; m <<= 1) {
        mx = fmaxf(mx, __shfl_xor(mx, m, 64));
    }

    const float ep = __expf(sp - mx);
    float num = ep * sp;
    float den = ep;
#pragma unroll
    for (int m = 8; m <= 32; m <<= 1) {
        num += __shfl_xor(num, m, 64);
        den += __shfl_xor(den, m, 64);
    }

    if (lane == 0) {
        out[e] = (num / den) * 11.313708498984761f; // sqrt(128)
    }
}

extern "C" void kernel_launch(void* const* d_in, const int* in_sizes, int n_in,
                              void* d_out, int out_size, void* d_ws, size_t ws_size,
                              hipStream_t stream) {
    const float* gnn_emb_src = (const float*)d_in[0];
    const float* gnn_emb_dst = (const float*)d_in[1];
    const float* news_pref   = (const float*)d_in[2];
    const float* last_update = (const float*)d_in[3];
    const float* time_arr    = (const float*)d_in[4];
    const int*   cate_id     = (const int*)d_in[5];
    const int*   src_idx     = (const int*)d_in[6];
    const int*   dst_idx     = (const int*)d_in[7];
    float* out = (float*)d_out;

    const int E = in_sizes[6];
    const int N_DST = in_sizes[1] / D;
    const int nkey = N_DST * N_CATE;
    const int nblk = (nkey + 1023) / 1024;

    // ws layout: cnt[nkey] | blk[256] | keys[E] | order[E]
    const size_t need = ((size_t)nkey + 256 + 2 * (size_t)E) * sizeof(int);
    int* order = nullptr;

    if (ws_size >= need && nblk <= 256) {
        int* cnt  = (int*)d_ws;
        int* blk  = cnt + nkey;
        int* keys = blk + 256;
        order     = keys + E;

        zero_kernel<<<(nkey + 255) / 256, 256, 0, stream>>>(cnt, nkey);
        hist_kernel<<<(E + 255) / 256, 256, 0, stream>>>(src_idx, dst_idx, cate_id, keys, cnt, E);
        scan_block_totals<<<nblk, 256, 0, stream>>>(cnt, blk, nkey);
        scan_totals<<<1, 256, 0, stream>>>(blk, nblk);
        scan_apply<<<nblk, 256, 0, stream>>>(cnt, blk, nkey);
        scatter_kernel<<<(E + 255) / 256, 256, 0, stream>>>(keys, cnt, order, E);
    }

    const int waves_per_block = 256 / 64;
    const int grid = (E + waves_per_block - 1) / waves_per_block;

    score_predictor_kernel<<<grid, 256, 0, stream>>>(
        gnn_emb_src, gnn_emb_dst, news_pref, last_update, time_arr,
        cate_id, src_idx, dst_idx, order, out, E);
}